// Round 1
// baseline (528.772 us; speedup 1.0000x reference)
//
#include <hip/hip_runtime.h>
#include <hip/hip_bf16.h>
#include <math.h>

#define B_      8
#define CIN     256
#define CMID    512
#define COUT    256
#define N_      2048
#define SCALE_  10.0f
#define EPS_THR 1e-3f
#define NORM_EPS_ 1e-12f

// ws layout (floats):
// [0, 131072)          W1t  [256][512]   (c-major)
// [131072, 262144)     W2t  [512][256]   (cc-major)
// [262144, 4456448)    qout [8][256][2048]
// [4456448, 8650752)   kout [8][256][2048]

// ---------------- Kernel 0: weight transpose ----------------
__global__ __launch_bounds__(256) void transpose_w(const float* __restrict__ W1,
                                                   const float* __restrict__ W2,
                                                   float* __restrict__ W1t,
                                                   float* __restrict__ W2t) {
    int idx = blockIdx.x * 256 + threadIdx.x;   // 0 .. 131071
    // W1: [512][256] row-major -> W1t[c*512 + o]
    {
        int o = idx >> 8;       // /256
        int c = idx & 255;
        W1t[c * 512 + o] = W1[idx];
    }
    // W2: [256][512] row-major -> W2t[cc*256 + o]
    {
        int o = idx >> 9;       // /512
        int cc = idx & 511;
        W2t[cc * 256 + o] = W2[idx];
    }
}

// ---------------- Kernel A: conv -> leaky -> conv -> l2norm ----------------
#define COLS 16

__device__ __forceinline__ void lds_load16(float (&v)[16], const float* s) {
    *(float4*)&v[0]  = *(const float4*)&s[0];
    *(float4*)&v[4]  = *(const float4*)&s[4];
    *(float4*)&v[8]  = *(const float4*)&s[8];
    *(float4*)&v[12] = *(const float4*)&s[12];
}

__global__ __launch_bounds__(256) void conv_norm(const float* __restrict__ q,
                                                 const float* __restrict__ k,
                                                 const float* __restrict__ W1t,
                                                 const float* __restrict__ W2t,
                                                 float* __restrict__ qo,
                                                 float* __restrict__ ko) {
    const float* x = blockIdx.y ? k : q;
    float* o       = blockIdx.y ? ko : qo;
    const int nb = N_ / COLS;                 // 128
    int b  = blockIdx.x / nb;
    int n0 = (blockIdx.x % nb) * COLS;
    int tid = threadIdx.x;

    __shared__ float xs[CIN * COLS];          // 16 KB (reused as reduction buf)
    __shared__ float hs[CMID * COLS];         // 32 KB

    // phase 1: stage x columns
    {
        const float* src = x + ((size_t)b * CIN + tid) * N_ + n0;
        float4* dst = (float4*)&xs[tid * COLS];
        dst[0] = ((const float4*)src)[0];
        dst[1] = ((const float4*)src)[1];
        dst[2] = ((const float4*)src)[2];
        dst[3] = ((const float4*)src)[3];
    }
    __syncthreads();

    // phase 2: h rows tid and tid+256
    float acc0[COLS], acc1[COLS];
#pragma unroll
    for (int j = 0; j < COLS; ++j) { acc0[j] = 0.f; acc1[j] = 0.f; }
    for (int c = 0; c < CIN; ++c) {
        float w0 = W1t[c * CMID + tid];
        float w1 = W1t[c * CMID + tid + 256];
        float xv[16];
        lds_load16(xv, &xs[c * COLS]);
#pragma unroll
        for (int j = 0; j < COLS; ++j) {
            acc0[j] += w0 * xv[j];
            acc1[j] += w1 * xv[j];
        }
    }
#pragma unroll
    for (int j = 0; j < COLS; ++j) {
        float a = acc0[j];
        hs[tid * COLS + j] = (a >= 0.f) ? a : 0.01f * a;
        float bb = acc1[j];
        hs[(tid + 256) * COLS + j] = (bb >= 0.f) ? bb : 0.01f * bb;
    }
    __syncthreads();

    // phase 3: y row tid
    float acc[COLS];
#pragma unroll
    for (int j = 0; j < COLS; ++j) acc[j] = 0.f;
    for (int cc = 0; cc < CMID; ++cc) {
        float w = W2t[cc * COUT + tid];
        float hv[16];
        lds_load16(hv, &hs[cc * COLS]);
#pragma unroll
        for (int j = 0; j < COLS; ++j) acc[j] += w * hv[j];
    }

    // column-wise sum of squares across the 256 rows (threads)
#pragma unroll
    for (int j = 0; j < COLS; ++j) xs[tid * COLS + j] = acc[j] * acc[j];
    __syncthreads();
    for (int s = 128; s > 0; s >>= 1) {
        if (tid < s) {
#pragma unroll
            for (int j = 0; j < COLS; ++j)
                xs[tid * COLS + j] += xs[(tid + s) * COLS + j];
        }
        __syncthreads();
    }

#pragma unroll
    for (int j = 0; j < COLS; ++j) {
        float nrm = sqrtf(xs[j]);
        float inv = 1.0f / fmaxf(nrm, NORM_EPS_);
        acc[j] *= inv;
    }
    float* dst = o + ((size_t)b * COUT + tid) * N_ + n0;
    ((float4*)dst)[0] = *(float4*)&acc[0];
    ((float4*)dst)[1] = *(float4*)&acc[4];
    ((float4*)dst)[2] = *(float4*)&acc[8];
    ((float4*)dst)[3] = *(float4*)&acc[12];
}

// ---------------- Kernel B: scores = 10 * qo^T ko ----------------
#define BQ 64
#define BK 64
#define KC 32

__global__ __launch_bounds__(256) void scores_kern(const float* __restrict__ qo,
                                                   const float* __restrict__ ko,
                                                   float* __restrict__ out) {
    int b  = blockIdx.z;
    int q0 = blockIdx.y * BQ;
    int k0 = blockIdx.x * BK;
    int tid = threadIdx.x;

    __shared__ float As[KC * BQ];   // 8 KB
    __shared__ float Bs[KC * BK];   // 8 KB

    float acc[4][4] = {};
    int tq = (tid / 16) * 4;
    int tk = (tid % 16) * 4;

    int lcc = tid / 8;              // 0..31
    int lq  = (tid % 8) * 8;        // 0,8,..,56
    const float* aptr = qo + ((size_t)b * COUT + lcc) * N_ + q0 + lq;
    const float* bptr = ko + ((size_t)b * COUT + lcc) * N_ + k0 + lq;

    for (int c0 = 0; c0 < COUT; c0 += KC) {
        *(float4*)&As[lcc * BQ + lq]     = *(const float4*)(aptr);
        *(float4*)&As[lcc * BQ + lq + 4] = *(const float4*)(aptr + 4);
        *(float4*)&Bs[lcc * BK + lq]     = *(const float4*)(bptr);
        *(float4*)&Bs[lcc * BK + lq + 4] = *(const float4*)(bptr + 4);
        aptr += (size_t)KC * N_;
        bptr += (size_t)KC * N_;
        __syncthreads();
#pragma unroll
        for (int cc = 0; cc < KC; ++cc) {
            float4 av = *(const float4*)&As[cc * BQ + tq];
            float4 bv = *(const float4*)&Bs[cc * BK + tk];
            float a_[4] = {av.x, av.y, av.z, av.w};
            float b_[4] = {bv.x, bv.y, bv.z, bv.w};
#pragma unroll
            for (int i = 0; i < 4; ++i)
#pragma unroll
                for (int j = 0; j < 4; ++j) acc[i][j] += a_[i] * b_[j];
        }
        __syncthreads();
    }

    size_t base = (size_t)b * N_ * N_ + (size_t)(q0 + tq) * N_ + k0 + tk;
#pragma unroll
    for (int i = 0; i < 4; ++i) {
        float4 v;
        v.x = acc[i][0] * SCALE_;
        v.y = acc[i][1] * SCALE_;
        v.z = acc[i][2] * SCALE_;
        v.w = acc[i][3] * SCALE_;
        *(float4*)&out[base + (size_t)i * N_] = v;
    }
}

// ---------------- Kernel C: in-place row softmax + threshold ----------------
__global__ __launch_bounds__(256) void softmax_thr(float* __restrict__ out) {
    size_t row = blockIdx.x;
    float* p = out + row * N_;
    int tid = threadIdx.x;
    int wid = tid >> 6, lane = tid & 63;

    float4 v0 = ((const float4*)p)[tid];
    float4 v1 = ((const float4*)p)[tid + 256];

    float m = fmaxf(fmaxf(fmaxf(v0.x, v0.y), fmaxf(v0.z, v0.w)),
                    fmaxf(fmaxf(v1.x, v1.y), fmaxf(v1.z, v1.w)));
#pragma unroll
    for (int off = 32; off; off >>= 1) m = fmaxf(m, __shfl_xor(m, off, 64));

    __shared__ float sm[4], ss[4];
    if (lane == 0) sm[wid] = m;
    __syncthreads();
    m = fmaxf(fmaxf(sm[0], sm[1]), fmaxf(sm[2], sm[3]));

    float e[8];
    e[0] = expf(v0.x - m); e[1] = expf(v0.y - m);
    e[2] = expf(v0.z - m); e[3] = expf(v0.w - m);
    e[4] = expf(v1.x - m); e[5] = expf(v1.y - m);
    e[6] = expf(v1.z - m); e[7] = expf(v1.w - m);
    float s = e[0] + e[1] + e[2] + e[3] + e[4] + e[5] + e[6] + e[7];
#pragma unroll
    for (int off = 32; off; off >>= 1) s += __shfl_xor(s, off, 64);
    if (lane == 0) ss[wid] = s;
    __syncthreads();
    s = ss[0] + ss[1] + ss[2] + ss[3];
    float inv = 1.0f / s;

    float4 w0, w1;
    float t;
    t = e[0] * inv; w0.x = (t > EPS_THR) ? t : 0.f;
    t = e[1] * inv; w0.y = (t > EPS_THR) ? t : 0.f;
    t = e[2] * inv; w0.z = (t > EPS_THR) ? t : 0.f;
    t = e[3] * inv; w0.w = (t > EPS_THR) ? t : 0.f;
    t = e[4] * inv; w1.x = (t > EPS_THR) ? t : 0.f;
    t = e[5] * inv; w1.y = (t > EPS_THR) ? t : 0.f;
    t = e[6] * inv; w1.z = (t > EPS_THR) ? t : 0.f;
    t = e[7] * inv; w1.w = (t > EPS_THR) ? t : 0.f;
    ((float4*)p)[tid]       = w0;
    ((float4*)p)[tid + 256] = w1;
}

// ---------------- Kernel D: copy key to output tail ----------------
__global__ __launch_bounds__(256) void copy_key(const float* __restrict__ in,
                                                float* __restrict__ dst, int n4) {
    int i = blockIdx.x * 256 + threadIdx.x;
    if (i < n4) ((float4*)dst)[i] = ((const float4*)in)[i];
}

extern "C" void kernel_launch(void* const* d_in, const int* in_sizes, int n_in,
                              void* d_out, int out_size, void* d_ws, size_t ws_size,
                              hipStream_t stream) {
    const float* q  = (const float*)d_in[0];
    const float* k  = (const float*)d_in[1];
    const float* W1 = (const float*)d_in[2];
    const float* W2 = (const float*)d_in[3];
    float* out = (float*)d_out;
    float* ws  = (float*)d_ws;

    float* W1t = ws;
    float* W2t = ws + 131072;
    float* qo  = ws + 262144;
    float* ko  = ws + 4456448;

    transpose_w<<<512, 256, 0, stream>>>(W1, W2, W1t, W2t);
    conv_norm<<<dim3(B_ * (N_ / COLS), 2), 256, 0, stream>>>(q, k, W1t, W2t, qo, ko);
    scores_kern<<<dim3(N_ / BK, N_ / BQ, B_), 256, 0, stream>>>(qo, ko, out);
    softmax_thr<<<B_ * N_, 256, 0, stream>>>(out);
    copy_key<<<4096, 256, 0, stream>>>(k, out + (size_t)B_ * N_ * N_, (B_ * CIN * N_) / 4);
}

// Round 2
// 149.706 us; speedup vs baseline: 3.5321x; 3.5321x over previous
//
#include <hip/hip_runtime.h>
#include <hip/hip_bf16.h>
#include <math.h>

#define B_      8
#define CIN     256
#define CMID    512
#define COUT    256
#define N_      2048
#define SCALE_  10.0f
#define EPS_THR 1e-3f
#define NORM_EPS_ 1e-12f

typedef __attribute__((ext_vector_type(8))) short short8;
typedef __attribute__((ext_vector_type(4))) float f32x4;

__device__ __forceinline__ ushort f2bf(float x) {
    union { float f; uint u; } v; v.f = x;
    uint r = v.u + 0x7FFF + ((v.u >> 16) & 1);
    return (ushort)(r >> 16);
}
__device__ __forceinline__ float bf2f(ushort h) {
    union { uint u; float f; } v; v.u = ((uint)h) << 16;
    return v.f;
}
__device__ __forceinline__ void gload_lds16(const void* g, void* l) {
    __builtin_amdgcn_global_load_lds((const __attribute__((address_space(1))) void*)g,
                                     (__attribute__((address_space(3))) void*)l, 16, 0, 0);
}

// ---------------- K0: weights fp32 -> bf16 (layout unchanged, row-major = K-contig) ---
__global__ __launch_bounds__(256) void prep_w(const float* __restrict__ W1,
                                              const float* __restrict__ W2,
                                              ushort* __restrict__ W1b,
                                              ushort* __restrict__ W2b) {
    int idx = blockIdx.x * 256 + threadIdx.x;   // 0..131071
    W1b[idx] = f2bf(W1[idx]);
    W2b[idx] = f2bf(W2[idx]);
}

// ---------------- K1: transpose q,k [B][C][N] fp32 -> Xt [32768][256] bf16 ----------
__global__ __launch_bounds__(256) void transpose_in(const float* __restrict__ q,
                                                    const float* __restrict__ k,
                                                    ushort* __restrict__ Xt) {
    __shared__ float t[64][65];
    int z = blockIdx.z;                   // 0..7 = q batches, 8..15 = k batches
    const float* src = (z < 8) ? q : k;
    int b = z & 7;
    size_t rowbase = (size_t)(z < 8 ? b : 8 + b) * N_;
    int c0 = blockIdx.y * 64;
    int n0 = blockIdx.x * 64;
    int rs = threadIdx.x >> 6;            // 0..3
    int nl = threadIdx.x & 63;

    const float* sp = src + ((size_t)b * CIN + c0) * N_ + n0;
#pragma unroll
    for (int i = 0; i < 16; ++i) {
        int cl = i * 4 + rs;
        t[cl][nl] = sp[(size_t)cl * N_ + nl];
    }
    __syncthreads();
#pragma unroll
    for (int i = 0; i < 16; ++i) {
        int nloc = i * 4 + rs;
        Xt[(rowbase + n0 + nloc) * CIN + c0 + nl] = f2bf(t[nl][nloc]);
    }
}

// ---------------- K2: NT bf16 MFMA GEMM, 128x128 tile, m97 structure ----------------
// C[m][n] = sum_k A[m][k] * B[n][k];  A,B row-major bf16 with ld == K.
// MODE 0: leaky -> bf16    MODE 1: -> bf16    MODE 2: *10 -> fp32
template<int MODE>
__global__ __launch_bounds__(256) void gemm_nt(const ushort* __restrict__ A,
                                               const ushort* __restrict__ Bm,
                                               void* __restrict__ OutP,
                                               int K, int ldo,
                                               long zsA, long zsB, long zsO) {
    __shared__ ushort As[128 * 32];   // 8 KB
    __shared__ ushort Bs[128 * 32];   // 8 KB
    int tid = threadIdx.x;
    int lane = tid & 63, wave = tid >> 6;
    int wm = wave >> 1, wn = wave & 1;
    size_t m0 = (size_t)blockIdx.y * 128;
    size_t n0 = (size_t)blockIdx.x * 128;
    const ushort* Ab = A + (size_t)blockIdx.z * zsA;
    const ushort* Bb = Bm + (size_t)blockIdx.z * zsB;

    // staging: 512 slots of 16B per buffer; slot s -> row s>>2, k-chunk (s&3)*8
    int s0 = wave * 64 + lane;                       // 0..255
    const ushort* ag0 = Ab + (m0 + (s0 >> 2)) * (size_t)K + (s0 & 3) * 8;
    const ushort* bg0 = Bb + (n0 + (s0 >> 2)) * (size_t)K + (s0 & 3) * 8;
    size_t half = (size_t)64 * K;                    // slot+256 => row+64
    ushort* al0 = As + s0 * 8;
    ushort* al1 = As + (s0 + 256) * 8;
    ushort* bl0 = Bs + s0 * 8;
    ushort* bl1 = Bs + (s0 + 256) * 8;

    f32x4 acc[4][4];
#pragma unroll
    for (int i = 0; i < 4; ++i)
#pragma unroll
        for (int j = 0; j < 4; ++j) acc[i][j] = (f32x4)0.f;

    int mrow = lane & 15;
    int ksel = (lane >> 4) * 8;

    for (int k0 = 0; k0 < K; k0 += 32) {
        gload_lds16(ag0, al0);
        gload_lds16(ag0 + half, al1);
        gload_lds16(bg0, bl0);
        gload_lds16(bg0 + half, bl1);
        ag0 += 32; bg0 += 32;
        __syncthreads();

        short8 af[4], bf[4];
#pragma unroll
        for (int mi = 0; mi < 4; ++mi)
            af[mi] = *(const short8*)&As[(wm * 64 + mi * 16 + mrow) * 32 + ksel];
#pragma unroll
        for (int ni = 0; ni < 4; ++ni)
            bf[ni] = *(const short8*)&Bs[(wn * 64 + ni * 16 + mrow) * 32 + ksel];
#pragma unroll
        for (int mi = 0; mi < 4; ++mi)
#pragma unroll
            for (int ni = 0; ni < 4; ++ni)
                acc[mi][ni] = __builtin_amdgcn_mfma_f32_16x16x32_bf16(af[mi], bf[ni], acc[mi][ni], 0, 0, 0);
        __syncthreads();
    }

    int col = lane & 15, r0 = (lane >> 4) * 4;
#pragma unroll
    for (int mi = 0; mi < 4; ++mi) {
#pragma unroll
        for (int ni = 0; ni < 4; ++ni) {
#pragma unroll
            for (int r = 0; r < 4; ++r) {
                size_t rg = m0 + wm * 64 + mi * 16 + r0 + r;
                size_t cg = n0 + wn * 64 + ni * 16 + col;
                float v = acc[mi][ni][r];
                if (MODE == 0) {
                    v = (v >= 0.f) ? v : 0.01f * v;
                    ((ushort*)OutP)[((size_t)blockIdx.z * zsO) + rg * ldo + cg] = f2bf(v);
                } else if (MODE == 1) {
                    ((ushort*)OutP)[((size_t)blockIdx.z * zsO) + rg * ldo + cg] = f2bf(v);
                } else {
                    ((float*)OutP)[((size_t)blockIdx.z * zsO) + rg * ldo + cg] = v * SCALE_;
                }
            }
        }
    }
}

// ---------------- K3: per-row L2 norm, Y [32768][256] bf16 -> QK bf16 ---------------
__global__ __launch_bounds__(256) void norm_rows(const ushort* __restrict__ Y,
                                                 ushort* __restrict__ Q) {
    int row = blockIdx.x * 4 + (threadIdx.x >> 6);
    int lane = threadIdx.x & 63;
    const ushort* p = Y + (size_t)row * COUT + lane * 4;
    ushort4 v = *(const ushort4*)p;
    float f0 = bf2f(v.x), f1 = bf2f(v.y), f2 = bf2f(v.z), f3 = bf2f(v.w);
    float s = f0 * f0 + f1 * f1 + f2 * f2 + f3 * f3;
#pragma unroll
    for (int off = 32; off; off >>= 1) s += __shfl_xor(s, off, 64);
    float inv = 1.0f / fmaxf(sqrtf(s), NORM_EPS_);
    ushort4 o;
    o.x = f2bf(f0 * inv); o.y = f2bf(f1 * inv);
    o.z = f2bf(f2 * inv); o.w = f2bf(f3 * inv);
    *(ushort4*)(Q + (size_t)row * COUT + lane * 4) = o;
}

// ---------------- K4: in-place row softmax + threshold ------------------------------
__global__ __launch_bounds__(256) void softmax_thr(float* __restrict__ out) {
    size_t row = blockIdx.x;
    float* p = out + row * N_;
    int tid = threadIdx.x;
    int wid = tid >> 6, lane = tid & 63;

    float4 v0 = ((const float4*)p)[tid];
    float4 v1 = ((const float4*)p)[tid + 256];

    float m = fmaxf(fmaxf(fmaxf(v0.x, v0.y), fmaxf(v0.z, v0.w)),
                    fmaxf(fmaxf(v1.x, v1.y), fmaxf(v1.z, v1.w)));
#pragma unroll
    for (int off = 32; off; off >>= 1) m = fmaxf(m, __shfl_xor(m, off, 64));

    __shared__ float sm[4], ss[4];
    if (lane == 0) sm[wid] = m;
    __syncthreads();
    m = fmaxf(fmaxf(sm[0], sm[1]), fmaxf(sm[2], sm[3]));

    float e[8];
    e[0] = expf(v0.x - m); e[1] = expf(v0.y - m);
    e[2] = expf(v0.z - m); e[3] = expf(v0.w - m);
    e[4] = expf(v1.x - m); e[5] = expf(v1.y - m);
    e[6] = expf(v1.z - m); e[7] = expf(v1.w - m);
    float s = e[0] + e[1] + e[2] + e[3] + e[4] + e[5] + e[6] + e[7];
#pragma unroll
    for (int off = 32; off; off >>= 1) s += __shfl_xor(s, off, 64);
    if (lane == 0) ss[wid] = s;
    __syncthreads();
    s = ss[0] + ss[1] + ss[2] + ss[3];
    float inv = 1.0f / s;

    float4 w0, w1;
    float t;
    t = e[0] * inv; w0.x = (t > EPS_THR) ? t : 0.f;
    t = e[1] * inv; w0.y = (t > EPS_THR) ? t : 0.f;
    t = e[2] * inv; w0.z = (t > EPS_THR) ? t : 0.f;
    t = e[3] * inv; w0.w = (t > EPS_THR) ? t : 0.f;
    t = e[4] * inv; w1.x = (t > EPS_THR) ? t : 0.f;
    t = e[5] * inv; w1.y = (t > EPS_THR) ? t : 0.f;
    t = e[6] * inv; w1.z = (t > EPS_THR) ? t : 0.f;
    t = e[7] * inv; w1.w = (t > EPS_THR) ? t : 0.f;
    ((float4*)p)[tid]       = w0;
    ((float4*)p)[tid + 256] = w1;
}

// ---------------- K5: copy key to output tail ---------------------------------------
__global__ __launch_bounds__(256) void copy_key(const float* __restrict__ in,
                                                float* __restrict__ dst, int n4) {
    int i = blockIdx.x * 256 + threadIdx.x;
    if (i < n4) ((float4*)dst)[i] = ((const float4*)in)[i];
}

extern "C" void kernel_launch(void* const* d_in, const int* in_sizes, int n_in,
                              void* d_out, int out_size, void* d_ws, size_t ws_size,
                              hipStream_t stream) {
    const float* q  = (const float*)d_in[0];
    const float* k  = (const float*)d_in[1];
    const float* W1 = (const float*)d_in[2];
    const float* W2 = (const float*)d_in[3];
    float* out = (float*)d_out;

    // ws: W1b | W2b | QK  (17.3 MB)
    ushort* W1b = (ushort*)d_ws;
    ushort* W2b = W1b + 131072;
    ushort* QK  = W2b + 131072;                       // [32768][256] bf16

    // scratch inside d_out's scores region (first 134 MB, overwritten by scores GEMM):
    char* ob = (char*)d_out;
    ushort* Xt = (ushort*)ob;                          // [32768][256] bf16, 16.8 MB
    ushort* H  = (ushort*)(ob + 16777216);             // [32768][512] bf16, 33.5 MB
    ushort* Y  = (ushort*)(ob + 50331648);             // [32768][256] bf16, 16.8 MB

    prep_w<<<512, 256, 0, stream>>>(W1, W2, W1b, W2b);
    transpose_in<<<dim3(32, 4, 16), 256, 0, stream>>>(q, k, Xt);
    // H = leaky(Xt * W1^T)
    gemm_nt<0><<<dim3(4, 256, 1), 256, 0, stream>>>(Xt, W1b, H, 256, 512, 0, 0, 0);
    // Y = H * W2^T
    gemm_nt<1><<<dim3(2, 256, 1), 256, 0, stream>>>(H, W2b, Y, 512, 256, 0, 0, 0);
    norm_rows<<<8192, 256, 0, stream>>>(Y, QK);
    // scores[b] = 10 * Qn[b] * Kn[b]^T   (Qn rows 0..16383, Kn rows 16384..32767)
    gemm_nt<2><<<dim3(16, 16, 8), 256, 0, stream>>>(QK, QK + (size_t)16384 * 256, out,
                                                    256, 2048,
                                                    (long)2048 * 256, (long)2048 * 256,
                                                    (long)2048 * 2048);
    softmax_thr<<<B_ * N_, 256, 0, stream>>>(out);
    copy_key<<<4096, 256, 0, stream>>>(k, out + (size_t)B_ * N_ * N_, (B_ * CIN * N_) / 4);
}